// Round 1
// baseline (485.726 us; speedup 1.0000x reference)
//
#include <hip/hip_runtime.h>

#define NROWS 8192
#define DIM   128
#define BM    64
#define BN    64
#define LDK   136   // padded LDS row stride in bf16 elements (272 B = 17*16B -> 16B aligned, 2-way bank alias only)

typedef __attribute__((ext_vector_type(8))) __bf16 bf16x8;
typedef __attribute__((ext_vector_type(4))) float  f32x4;

constexpr float INV_T = 1.0f / 0.07f;
constexpr float EPSF  = 1e-8f;

// One wave per row: fp32 -> bf16 convert + fp32 norm.
__global__ __launch_bounds__(256)
void prep_kernel(const float* __restrict__ e1, const float* __restrict__ e2,
                 __bf16* __restrict__ b1, __bf16* __restrict__ b2,
                 float* __restrict__ n1, float* __restrict__ n2) {
    int gw   = (blockIdx.x * 256 + threadIdx.x) >> 6;   // global wave id, 0..16383
    int lane = threadIdx.x & 63;
    const float* src; __bf16* dst; float* nrm; int row;
    if (gw < NROWS) { src = e1; dst = b1; nrm = n1; row = gw; }
    else            { src = e2; dst = b2; nrm = n2; row = gw - NROWS; }
    float2 v = ((const float2*)(src + (size_t)row * DIM))[lane];
    float ss = v.x * v.x + v.y * v.y;
    dst[(size_t)row * DIM + 2 * lane]     = (__bf16)v.x;
    dst[(size_t)row * DIM + 2 * lane + 1] = (__bf16)v.y;
#pragma unroll
    for (int o = 32; o > 0; o >>= 1) ss += __shfl_down(ss, o);
    if (lane == 0) nrm[row] = sqrtf(ss);
}

// One 64x64 output tile per block; computes sim11 & sim12 contributions fused.
__global__ __launch_bounds__(256)
void sim_kernel(const __bf16* __restrict__ E1, const __bf16* __restrict__ E2,
                const float* __restrict__ N1, const float* __restrict__ N2,
                float* __restrict__ acc) {
    __shared__ __align__(16) __bf16 As [BM * LDK];
    __shared__ __align__(16) __bf16 Bs1[BN * LDK];
    __shared__ __align__(16) __bf16 Bs2[BN * LDK];
    __shared__ float red[8];

    const int tid  = threadIdx.x;
    const int bj   = blockIdx.x, bi = blockIdx.y;
    const int row0 = bi * BM,    col0 = bj * BN;

    // Stage 3 tiles: each tile is 64 rows x 128 bf16 = 1024 16B-chunks.
#pragma unroll
    for (int it = 0; it < 4; ++it) {
        int idx = tid + it * 256;
        int r = idx >> 4, c = idx & 15;
        uint4 va  = *(const uint4*)(E1 + (size_t)(row0 + r) * DIM + c * 8);
        *(uint4*)(&As [r * LDK + c * 8]) = va;
        uint4 vb1 = *(const uint4*)(E1 + (size_t)(col0 + r) * DIM + c * 8);
        *(uint4*)(&Bs1[r * LDK + c * 8]) = vb1;
        uint4 vb2 = *(const uint4*)(E2 + (size_t)(col0 + r) * DIM + c * 8);
        *(uint4*)(&Bs2[r * LDK + c * 8]) = vb2;
    }
    __syncthreads();

    const int wave = tid >> 6, lane = tid & 63;
    const int quad = lane >> 4, l16 = lane & 15;
    const int mb   = wave * 16;          // this wave's 16 output rows within the tile

    // A fragments: A[m = lane&15][k = quad*8 + j], 4 k-chunks of 32.
    bf16x8 af[4];
#pragma unroll
    for (int k = 0; k < 4; ++k)
        af[k] = *(const bf16x8*)(&As[(mb + l16) * LDK + k * 32 + quad * 8]);

    f32x4 c1[4], c2[4];
#pragma unroll
    for (int n = 0; n < 4; ++n) {
        c1[n] = f32x4{0.f, 0.f, 0.f, 0.f};
        c2[n] = f32x4{0.f, 0.f, 0.f, 0.f};
    }

#pragma unroll
    for (int n = 0; n < 4; ++n) {
#pragma unroll
        for (int k = 0; k < 4; ++k) {
            bf16x8 bf = *(const bf16x8*)(&Bs1[(n * 16 + l16) * LDK + k * 32 + quad * 8]);
            c1[n] = __builtin_amdgcn_mfma_f32_16x16x32_bf16(af[k], bf, c1[n], 0, 0, 0);
        }
#pragma unroll
        for (int k = 0; k < 4; ++k) {
            bf16x8 bf = *(const bf16x8*)(&Bs2[(n * 16 + l16) * LDK + k * 32 + quad * 8]);
            c2[n] = __builtin_amdgcn_mfma_f32_16x16x32_bf16(af[k], bf, c2[n], 0, 0, 0);
        }
    }

    // Epilogue: C/D layout col = lane&15, row = quad*4 + reg (m89/m91 verified).
    float ni[4]; int ig[4];
#pragma unroll
    for (int r = 0; r < 4; ++r) {
        ig[r] = row0 + mb + quad * 4 + r;
        ni[r] = N1[ig[r]];
    }
    float s1 = 0.f, s2 = 0.f;
#pragma unroll
    for (int n = 0; n < 4; ++n) {
        int   cg  = col0 + n * 16 + l16;
        float nj1 = N1[cg], nj2 = N2[cg];
#pragma unroll
        for (int r = 0; r < 4; ++r) {
            float den1  = fmaxf(ni[r] * nj1, EPSF);
            float sim11 = c1[n][r] * __builtin_amdgcn_rcpf(den1);
            int dd = cg - ig[r]; dd += (dd >> 31) & NROWS;   // (cg - ig) mod 8192
            float ev1 = __expf(sim11 * INV_T);
            if (dd > ig[r]) s1 += ev1;                       // j in [i+1, B)
            float den2  = fmaxf(ni[r] * nj2, EPSF);
            float sim12 = c2[n][r] * __builtin_amdgcn_rcpf(den2);
            s2 += __expf(sim12 * INV_T);
        }
    }
#pragma unroll
    for (int o = 32; o > 0; o >>= 1) {
        s1 += __shfl_down(s1, o);
        s2 += __shfl_down(s2, o);
    }
    if (lane == 0) { red[wave] = s1; red[4 + wave] = s2; }
    __syncthreads();
    if (tid == 0) {
        atomicAdd(&acc[0], red[0] + red[1] + red[2] + red[3]);
        atomicAdd(&acc[1], red[4] + red[5] + red[6] + red[7]);
    }
}

__global__ void finalize_kernel(const float* __restrict__ acc, float* __restrict__ out) {
    if (threadIdx.x == 0) out[0] = -logf(acc[0] / acc[1]);
}

extern "C" void kernel_launch(void* const* d_in, const int* in_sizes, int n_in,
                              void* d_out, int out_size, void* d_ws, size_t ws_size,
                              hipStream_t stream) {
    (void)in_sizes; (void)n_in; (void)out_size; (void)ws_size;
    const float* e1 = (const float*)d_in[0];
    const float* e2 = (const float*)d_in[1];
    float* out = (float*)d_out;
    char*  ws  = (char*)d_ws;

    // Workspace layout (needs ~4.26 MB):
    float*  acc = (float*)ws;                               // 8 B
    float*  n1  = (float*)(ws + 4096);                      // 32 KB
    float*  n2  = (float*)(ws + 4096 + 32768);              // 32 KB
    __bf16* b1  = (__bf16*)(ws + 69632);                    // 2 MB, 256B aligned
    __bf16* b2  = (__bf16*)(ws + 69632 + 2097152);          // 2 MB

    hipMemsetAsync(acc, 0, 8, stream);
    prep_kernel<<<dim3(4096), dim3(256), 0, stream>>>(e1, e2, b1, b2, n1, n2);
    sim_kernel<<<dim3(128, 128), dim3(256), 0, stream>>>(b1, b2, n1, n2, acc);
    finalize_kernel<<<dim3(1), dim3(64), 0, stream>>>(acc, out);
}

// Round 2
// 149.750 us; speedup vs baseline: 3.2436x; 3.2436x over previous
//
#include <hip/hip_runtime.h>

#define B_ROWS 8192
#define DIM    128
#define TILE   128
#define LDK    136   // padded LDS row stride (bf16 elems): 272 B -> bank stride 4, conflict-free b128 phases

typedef __attribute__((ext_vector_type(8)))  __bf16 bf16x8;
typedef __attribute__((ext_vector_type(16))) float  f32x16;

// sqrt(log2(e)/0.07): fold temperature+log2e symmetrically into both row scales.
#define RBSCALE 4.5398172f

// One wave per row: fp32 -> bf16 convert + scaled reciprocal norm.
__global__ __launch_bounds__(256)
void prep_kernel(const float* __restrict__ e1, const float* __restrict__ e2,
                 __bf16* __restrict__ b1, __bf16* __restrict__ b2,
                 float* __restrict__ rb1, float* __restrict__ rb2) {
    int gw   = (blockIdx.x * 256 + threadIdx.x) >> 6;
    int lane = threadIdx.x & 63;
    const float* src; __bf16* dst; float* rb; int row;
    if (gw < B_ROWS) { src = e1; dst = b1; rb = rb1; row = gw; }
    else             { src = e2; dst = b2; rb = rb2; row = gw - B_ROWS; }
    float2 v = ((const float2*)(src + (size_t)row * DIM))[lane];
    float ss = v.x * v.x + v.y * v.y;
    dst[(size_t)row * DIM + 2 * lane]     = (__bf16)v.x;
    dst[(size_t)row * DIM + 2 * lane + 1] = (__bf16)v.y;
#pragma unroll
    for (int o = 32; o > 0; o >>= 1) ss += __shfl_down(ss, o);
    if (lane == 0) rb[row] = RBSCALE / sqrtf(ss);
}

template <bool MASKED>
__device__ __forceinline__ float epilogue_sum(const f32x16 acc[2][2], const float rn[2][16],
                                              float nc0, float nc1, int i0, int c0,
                                              int ra, int rbase, int l, int h) {
    float s = 0.f;
#pragma unroll
    for (int g = 0; g < 2; ++g) {
#pragma unroll
        for (int t = 0; t < 2; ++t) {
            float nc = t ? nc1 : nc0;
#pragma unroll
            for (int q = 0; q < 4; ++q) {
#pragma unroll
                for (int rr = 0; rr < 4; ++rr) {
                    float arg = acc[g][t][q * 4 + rr] * rn[g][q * 4 + rr] * nc;
                    float ev  = exp2f(arg);
                    if (MASKED) {
                        int i = i0 + ra + g * 32 + 8 * q + 4 * h + rr;
                        int c = c0 + rbase + t * 32 + l;
                        int d = c - i; d += (d >> 31) & B_ROWS;   // (c-i) mod B
                        s += (d > i) ? ev : 0.f;
                    } else {
                        s += ev;
                    }
                }
            }
        }
    }
    return s;
}

// One 128x128 tile of sim11 (z=0, masked triangle) or sim12 (z=1) per block.
__global__ __launch_bounds__(256, 2)
void pair_kernel(const __bf16* __restrict__ E1, const __bf16* __restrict__ E2,
                 const float* __restrict__ RB1, const float* __restrict__ RB2,
                 float* __restrict__ accg) {
    const int z  = blockIdx.z;
    const int i0 = blockIdx.y * TILE, c0 = blockIdx.x * TILE;

    bool masked = false;
    if (z == 0) {
        // d = (c-i) mod B; include tile iff some element has d > i.
        int D = c0 - i0;
        int e = (D > 0) ? D : D + B_ROWS;     // D==0 -> B (diagonal tiles always included)
        if (e + 127 <= i0) return;            // fully excluded tile
        masked = (D == 0) || (e <= i0 + 254); // partially-masked tile needs per-element test
    }

    const __bf16* Bsrc = (z == 0) ? E1 : E2;
    const float*  RC   = (z == 0) ? RB1 : RB2;

    __shared__ __align__(16) __bf16 As[TILE * LDK];
    __shared__ __align__(16) __bf16 Bs[TILE * LDK];
    __shared__ float sRow[TILE];
    __shared__ float sCol[TILE];
    __shared__ float red[4];

    const int tid = threadIdx.x;
#pragma unroll
    for (int it = 0; it < 8; ++it) {
        int idx = tid + it * 256;
        int r = idx >> 4, c = idx & 15;
        *(uint4*)(&As[r * LDK + c * 8]) = *(const uint4*)(E1   + (size_t)(i0 + r) * DIM + c * 8);
        *(uint4*)(&Bs[r * LDK + c * 8]) = *(const uint4*)(Bsrc + (size_t)(c0 + r) * DIM + c * 8);
    }
    if (tid < TILE) sRow[tid] = RB1[i0 + tid];
    else            sCol[tid - TILE] = RC[c0 + tid - TILE];
    __syncthreads();

    const int wave = tid >> 6, lane = tid & 63;
    const int wm = wave >> 1, wn = wave & 1;
    const int l  = lane & 31, h  = lane >> 5;
    const int ra = wm * 64, rbase = wn * 64;

    f32x16 acc[2][2];
#pragma unroll
    for (int g = 0; g < 2; ++g)
#pragma unroll
        for (int t = 0; t < 2; ++t)
#pragma unroll
            for (int q = 0; q < 16; ++q) acc[g][t][q] = 0.f;

    const __bf16* Ap = &As[(ra    + l) * LDK + h * 8];
    const __bf16* Bp = &Bs[(rbase + l) * LDK + h * 8];
#pragma unroll
    for (int s = 0; s < 8; ++s) {
        bf16x8 a0 = *(const bf16x8*)(Ap + s * 16);
        bf16x8 a1 = *(const bf16x8*)(Ap + 32 * LDK + s * 16);
        bf16x8 b0 = *(const bf16x8*)(Bp + s * 16);
        bf16x8 b1 = *(const bf16x8*)(Bp + 32 * LDK + s * 16);
        acc[0][0] = __builtin_amdgcn_mfma_f32_32x32x16_bf16(a0, b0, acc[0][0], 0, 0, 0);
        acc[0][1] = __builtin_amdgcn_mfma_f32_32x32x16_bf16(a0, b1, acc[0][1], 0, 0, 0);
        acc[1][0] = __builtin_amdgcn_mfma_f32_32x32x16_bf16(a1, b0, acc[1][0], 0, 0, 0);
        acc[1][1] = __builtin_amdgcn_mfma_f32_32x32x16_bf16(a1, b1, acc[1][1], 0, 0, 0);
    }

    // Row norms for this wave: C/D row = (reg&3) + 8*(reg>>2) + 4*h  (m74/m101 layout).
    float rn[2][16];
#pragma unroll
    for (int g = 0; g < 2; ++g)
#pragma unroll
        for (int q = 0; q < 4; ++q) {
            float4 v = *(const float4*)&sRow[ra + g * 32 + 8 * q + 4 * h];
            rn[g][q * 4 + 0] = v.x; rn[g][q * 4 + 1] = v.y;
            rn[g][q * 4 + 2] = v.z; rn[g][q * 4 + 3] = v.w;
        }
    const float nc0 = sCol[rbase + l];
    const float nc1 = sCol[rbase + 32 + l];

    float s_local = masked
        ? epilogue_sum<true >(acc, rn, nc0, nc1, i0, c0, ra, rbase, l, h)
        : epilogue_sum<false>(acc, rn, nc0, nc1, i0, c0, ra, rbase, l, h);

#pragma unroll
    for (int o = 32; o > 0; o >>= 1) s_local += __shfl_down(s_local, o);
    if (lane == 0) red[wave] = s_local;
    __syncthreads();
    if (tid == 0) atomicAdd(&accg[z], red[0] + red[1] + red[2] + red[3]);
}

__global__ void finalize_kernel(const float* __restrict__ acc, float* __restrict__ out) {
    if (threadIdx.x == 0) out[0] = -logf(acc[0] / acc[1]);
}

extern "C" void kernel_launch(void* const* d_in, const int* in_sizes, int n_in,
                              void* d_out, int out_size, void* d_ws, size_t ws_size,
                              hipStream_t stream) {
    (void)in_sizes; (void)n_in; (void)out_size; (void)ws_size;
    const float* e1 = (const float*)d_in[0];
    const float* e2 = (const float*)d_in[1];
    float* out = (float*)d_out;
    char*  ws  = (char*)d_ws;

    float*  acc = (float*)ws;                               // 8 B
    float*  rb1 = (float*)(ws + 4096);                      // 32 KB
    float*  rb2 = (float*)(ws + 4096 + 32768);              // 32 KB
    __bf16* b1  = (__bf16*)(ws + 69632);                    // 2 MB
    __bf16* b2  = (__bf16*)(ws + 69632 + 2097152);          // 2 MB

    hipMemsetAsync(acc, 0, 8, stream);
    prep_kernel<<<dim3(4096), dim3(256), 0, stream>>>(e1, e2, b1, b2, rb1, rb2);
    pair_kernel<<<dim3(64, 64, 2), dim3(256), 0, stream>>>(b1, b2, rb1, rb2, acc);
    finalize_kernel<<<dim3(1), dim3(64), 0, stream>>>(acc, out);
}